// Round 1
// baseline (2333.478 us; speedup 1.0000x reference)
//
#include <hip/hip_runtime.h>
#include <math.h>

#define SEQ  2048
#define BATCH 8
#define NTOK (SEQ*BATCH)   // 16384 tokens

// ---------------------------------------------------------------------------
// 1) h = x + positional encoding.  pe(s,d) = d%2==0 ? sin(s/10000^(d/256))
//                                              : cos(s/10000^(d/256))
// ---------------------------------------------------------------------------
__global__ __launch_bounds__(256) void add_pe_kernel(const float* __restrict__ x,
                                                     float* __restrict__ h) {
    int idx = blockIdx.x * 256 + threadIdx.x;     // over SEQ*256
    int s = idx >> 8;
    int d = idx & 255;
    float p   = powf(10000.0f, (float)d * (1.0f / 256.0f));
    float ang = (float)s / p;
    float pe  = (d & 1) ? cosf(ang) : sinf(ang);
    #pragma unroll
    for (int b = 0; b < BATCH; ++b) {
        size_t g = ((size_t)(b * SEQ + s) << 8) + d;
        h[g] = x[g] + pe;
    }
}

// ---------------------------------------------------------------------------
// 2) fp32 tiled GEMM:  C[M,N] = A[M,K] @ W[K,N] + bias  (optional ReLU)
//    64x64 tile, BK=16, 256 threads, 4x4 per-thread microtile.
//    M,N multiples of 64; K multiple of 16 (true for every call here).
// ---------------------------------------------------------------------------
template<int RELU>
__global__ __launch_bounds__(256) void gemm_bias_kernel(
    const float* __restrict__ A, const float* __restrict__ W,
    const float* __restrict__ bias, float* __restrict__ C,
    int M, int N, int K)
{
    __shared__ float As[16][72];   // [k][m], 72-float rows keep float4 alignment
    __shared__ float Bs[16][72];   // [k][n]
    const int bm  = blockIdx.y * 64;
    const int bn  = blockIdx.x * 64;
    const int tid = threadIdx.x;
    const int tx  = tid & 15, ty = tid >> 4;

    float acc[4][4] = {{0.f}};

    for (int k0 = 0; k0 < K; k0 += 16) {
        #pragma unroll
        for (int i = 0; i < 4; ++i) {           // A tile: 64 rows x 16 k
            int f = tid + 256 * i;
            int row = f >> 4, kk = f & 15;
            As[kk][row] = A[(size_t)(bm + row) * K + k0 + kk];
        }
        #pragma unroll
        for (int i = 0; i < 4; ++i) {           // B tile: 16 k x 64 n
            int f = tid + 256 * i;
            int kk = f >> 6, n = f & 63;
            Bs[kk][n] = W[(size_t)(k0 + kk) * N + bn + n];
        }
        __syncthreads();
        #pragma unroll
        for (int kk = 0; kk < 16; ++kk) {
            float4 a4 = *(const float4*)&As[kk][ty * 4];
            float4 b4 = *(const float4*)&Bs[kk][tx * 4];
            float av[4] = {a4.x, a4.y, a4.z, a4.w};
            float bv[4] = {b4.x, b4.y, b4.z, b4.w};
            #pragma unroll
            for (int i = 0; i < 4; ++i)
                #pragma unroll
                for (int j = 0; j < 4; ++j)
                    acc[i][j] = fmaf(av[i], bv[j], acc[i][j]);
        }
        __syncthreads();
    }

    float4 b4 = *(const float4*)&bias[bn + tx * 4];
    float bv[4] = {b4.x, b4.y, b4.z, b4.w};
    #pragma unroll
    for (int i = 0; i < 4; ++i) {
        int row = bm + ty * 4 + i;
        float4 o;
        float v0 = acc[i][0] + bv[0];
        float v1 = acc[i][1] + bv[1];
        float v2 = acc[i][2] + bv[2];
        float v3 = acc[i][3] + bv[3];
        if (RELU) {
            v0 = fmaxf(v0, 0.f); v1 = fmaxf(v1, 0.f);
            v2 = fmaxf(v2, 0.f); v3 = fmaxf(v3, 0.f);
        }
        o.x = v0; o.y = v1; o.z = v2; o.w = v3;
        *(float4*)&C[(size_t)row * N + bn + tx * 4] = o;
    }
}

// ---------------------------------------------------------------------------
// 3) LayerNorm(a + r) * g + b, one wave per token row (D = 256 or 128)
// ---------------------------------------------------------------------------
template<int D>
__global__ __launch_bounds__(256) void ln_residual_kernel(
    const float* __restrict__ a, const float* __restrict__ r,
    const float* __restrict__ g, const float* __restrict__ bb,
    float* __restrict__ out)
{
    const int N = D >> 6;                 // elems per lane: 4 or 2
    int wave = threadIdx.x >> 6;
    int lane = threadIdx.x & 63;
    size_t token = (size_t)blockIdx.x * 4 + wave;
    const float* ar = a + token * D;
    const float* rr = r + token * D;
    float*      orow = out + token * D;

    float xv[N];
    float s = 0.f;
    #pragma unroll
    for (int i = 0; i < N; ++i) {
        int d = lane + (i << 6);
        xv[i] = ar[d] + rr[d];
        s += xv[i];
    }
    #pragma unroll
    for (int off = 1; off < 64; off <<= 1) s += __shfl_xor(s, off);
    float mean = s * (1.0f / D);
    float vs = 0.f;
    #pragma unroll
    for (int i = 0; i < N; ++i) { float d0 = xv[i] - mean; vs += d0 * d0; }
    #pragma unroll
    for (int off = 1; off < 64; off <<= 1) vs += __shfl_xor(vs, off);
    float inv = 1.0f / sqrtf(vs * (1.0f / D) + 1e-5f);
    #pragma unroll
    for (int i = 0; i < N; ++i) {
        int d = lane + (i << 6);
        orow[d] = (xv[i] - mean) * inv * g[d] + bb[d];
    }
}

// ---------------------------------------------------------------------------
// 4) Flash attention, fp32, 8 heads, head dim HD (32 or 16).
//    Layout [B, S, 8*HD].  One thread owns one q row; 256 q rows per block.
//    K/V staged in LDS in 64-key tiles; all inner LDS reads are broadcasts.
// ---------------------------------------------------------------------------
template<int HD>
__global__ __launch_bounds__(256) void flash_kernel(
    const float* __restrict__ Q, const float* __restrict__ Kp,
    const float* __restrict__ V, float* __restrict__ O)
{
    const int D = 8 * HD;
    const int LOG = (HD == 32) ? 5 : 4;
    const float scale = (HD == 32) ? (1.0f / 5.656854249492381f) : 0.25f;

    const int bh = blockIdx.y;             // 0..63  (b*8 + head)
    const int b  = bh >> 3, hh = bh & 7;
    const int qrow = blockIdx.x * 256 + threadIdx.x;
    const size_t base = (size_t)b * SEQ * D + hh * HD;

    float qv[HD];
    #pragma unroll
    for (int e4 = 0; e4 < HD / 4; ++e4) {
        float4 t = *(const float4*)&Q[base + (size_t)qrow * D + e4 * 4];
        qv[e4 * 4 + 0] = t.x * scale;
        qv[e4 * 4 + 1] = t.y * scale;
        qv[e4 * 4 + 2] = t.z * scale;
        qv[e4 * 4 + 3] = t.w * scale;
    }

    float m = -INFINITY, l = 0.f;
    float acc[HD];
    #pragma unroll
    for (int e = 0; e < HD; ++e) acc[e] = 0.f;

    __shared__ float Ks[64][HD];
    __shared__ float Vs[64][HD];

    for (int kt = 0; kt < SEQ; kt += 64) {
        __syncthreads();
        #pragma unroll
        for (int f0 = 0; f0 < 64 * HD; f0 += 256) {
            int f = f0 + threadIdx.x;
            int row = f >> LOG, e = f & (HD - 1);
            Ks[row][e] = Kp[base + (size_t)(kt + row) * D + e];
            Vs[row][e] = V [base + (size_t)(kt + row) * D + e];
        }
        __syncthreads();

        #pragma unroll
        for (int j0 = 0; j0 < 64; j0 += 16) {
            float sc[16];
            float tm = m;
            #pragma unroll
            for (int j = 0; j < 16; ++j) {
                float s = 0.f;
                #pragma unroll
                for (int e = 0; e < HD; ++e) s = fmaf(qv[e], Ks[j0 + j][e], s);
                sc[j] = s;
                tm = fmaxf(tm, s);
            }
            float resc = __expf(m - tm);   // m==-inf on first chunk -> 0
            m = tm;
            l *= resc;
            #pragma unroll
            for (int e = 0; e < HD; ++e) acc[e] *= resc;
            #pragma unroll
            for (int j = 0; j < 16; ++j) {
                float p = __expf(sc[j] - m);
                l += p;
                #pragma unroll
                for (int e = 0; e < HD; ++e) acc[e] = fmaf(p, Vs[j0 + j][e], acc[e]);
            }
        }
    }

    float invl = 1.0f / l;
    #pragma unroll
    for (int e4 = 0; e4 < HD / 4; ++e4) {
        float4 t;
        t.x = acc[e4 * 4 + 0] * invl;
        t.y = acc[e4 * 4 + 1] * invl;
        t.z = acc[e4 * 4 + 2] * invl;
        t.w = acc[e4 * 4 + 3] * invl;
        *(float4*)&O[base + (size_t)qrow * D + e4 * 4] = t;
    }
}

// ---------------------------------------------------------------------------
// 5) max over sequence dim:  in [B, S, 64] -> out [B, 64]
// ---------------------------------------------------------------------------
__global__ __launch_bounds__(256) void maxpool_kernel(const float* __restrict__ in,
                                                      float* __restrict__ out) {
    __shared__ float red[4][64];
    int b = blockIdx.x, d = threadIdx.x & 63, st = threadIdx.x >> 6;
    float m = -INFINITY;
    for (int s = st * (SEQ / 4); s < (st + 1) * (SEQ / 4); ++s)
        m = fmaxf(m, in[((size_t)b * SEQ + s) * 64 + d]);
    red[st][d] = m;
    __syncthreads();
    if (st == 0) {
        m = fmaxf(fmaxf(red[0][d], red[1][d]), fmaxf(red[2][d], red[3][d]));
        out[b * 64 + d] = m;
    }
}

// ---------------------------------------------------------------------------
// 6) head: pooled[8,64] @ w3[64,32]+b3 -> t[8,32];  t @ w4[32,14]+b4 -> out[8,14]
// ---------------------------------------------------------------------------
__global__ __launch_bounds__(256) void head_kernel(
    const float* __restrict__ pooled,
    const float* __restrict__ w3, const float* __restrict__ b3,
    const float* __restrict__ w4, const float* __restrict__ b4,
    float* __restrict__ out)
{
    __shared__ float t[8][32];
    int tid = threadIdx.x;
    {
        int b = tid >> 5, j = tid & 31;          // 256 threads = 8*32
        float s = b3[j];
        #pragma unroll
        for (int k = 0; k < 64; ++k) s = fmaf(pooled[b * 64 + k], w3[k * 32 + j], s);
        t[b][j] = s;
    }
    __syncthreads();
    if (tid < 8 * 14) {
        int b = tid / 14, j = tid % 14;
        float s = b4[j];
        #pragma unroll
        for (int k = 0; k < 32; ++k) s = fmaf(t[b][k], w4[k * 14 + j], s);
        out[b * 14 + j] = s;
    }
}

// ---------------------------------------------------------------------------
extern "C" void kernel_launch(void* const* d_in, const int* in_sizes, int n_in,
                              void* d_out, int out_size, void* d_ws, size_t ws_size,
                              hipStream_t stream) {
    const float* x     = (const float*)d_in[0];
    // block 1 (d=256)
    const float* qw1   = (const float*)d_in[1];
    const float* qb1   = (const float*)d_in[2];
    const float* kw1   = (const float*)d_in[3];
    const float* kb1   = (const float*)d_in[4];
    const float* vw1   = (const float*)d_in[5];
    const float* vb1   = (const float*)d_in[6];
    const float* ow1   = (const float*)d_in[7];
    const float* ob1   = (const float*)d_in[8];
    const float* f1w1  = (const float*)d_in[9];
    const float* f1b1  = (const float*)d_in[10];
    const float* f2w1  = (const float*)d_in[11];
    const float* f2b1  = (const float*)d_in[12];
    const float* ln1g1 = (const float*)d_in[13];
    const float* ln1b1 = (const float*)d_in[14];
    const float* ln2g1 = (const float*)d_in[15];
    const float* ln2b1 = (const float*)d_in[16];
    // block 2 (d=128)
    const float* qw2   = (const float*)d_in[17];
    const float* qb2   = (const float*)d_in[18];
    const float* kw2   = (const float*)d_in[19];
    const float* kb2   = (const float*)d_in[20];
    const float* vw2   = (const float*)d_in[21];
    const float* vb2   = (const float*)d_in[22];
    const float* ow2   = (const float*)d_in[23];
    const float* ob2   = (const float*)d_in[24];
    const float* f1w2  = (const float*)d_in[25];
    const float* f1b2  = (const float*)d_in[26];
    const float* f2w2  = (const float*)d_in[27];
    const float* f2b2  = (const float*)d_in[28];
    const float* ln1g2 = (const float*)d_in[29];
    const float* ln1b2 = (const float*)d_in[30];
    const float* ln2g2 = (const float*)d_in[31];
    const float* ln2b2 = (const float*)d_in[32];
    // dim-reduce layers
    const float* dr1w  = (const float*)d_in[33];
    const float* dr1b  = (const float*)d_in[34];
    const float* dr2w  = (const float*)d_in[35];
    const float* dr2b  = (const float*)d_in[36];
    const float* dr3w  = (const float*)d_in[37];
    const float* dr3b  = (const float*)d_in[38];
    const float* dr4w  = (const float*)d_in[39];
    const float* dr4b  = (const float*)d_in[40];

    const size_t T = NTOK;
    float* ws  = (float*)d_ws;
    float* h   = ws;                 // [T,256]
    float* q   = h   + T * 256;      // [T,256]
    float* k   = q   + T * 256;      // [T,256]
    float* v   = k   + T * 256;      // [T,256]
    float* o   = v   + T * 256;      // [T,256]
    float* big = o   + T * 256;      // [T,1024]

    const dim3 blk(256);
    const int MB = NTOK / 64;        // 256 M-tiles

    // ---- embed + PE ----
    add_pe_kernel<<<SEQ * 256 / 256, blk, 0, stream>>>(x, h);

    // ================= encoder 1 (d=256, ff=1024, hd=32) =================
    gemm_bias_kernel<0><<<dim3(4,  MB), blk, 0, stream>>>(h, qw1, qb1, q, NTOK, 256, 256);
    gemm_bias_kernel<0><<<dim3(4,  MB), blk, 0, stream>>>(h, kw1, kb1, k, NTOK, 256, 256);
    gemm_bias_kernel<0><<<dim3(4,  MB), blk, 0, stream>>>(h, vw1, vb1, v, NTOK, 256, 256);
    flash_kernel<32><<<dim3(SEQ / 256, 64), blk, 0, stream>>>(q, k, v, o);
    gemm_bias_kernel<0><<<dim3(4,  MB), blk, 0, stream>>>(o, ow1, ob1, big, NTOK, 256, 256);
    ln_residual_kernel<256><<<NTOK / 4, blk, 0, stream>>>(big, h, ln1g1, ln1b1, h);
    gemm_bias_kernel<1><<<dim3(16, MB), blk, 0, stream>>>(h, f1w1, f1b1, big, NTOK, 1024, 256);
    gemm_bias_kernel<0><<<dim3(4,  MB), blk, 0, stream>>>(big, f2w1, f2b1, q, NTOK, 256, 1024);
    ln_residual_kernel<256><<<NTOK / 4, blk, 0, stream>>>(q, h, ln2g1, ln2b1, h);

    // ---- 256 -> 128 ----
    gemm_bias_kernel<0><<<dim3(2,  MB), blk, 0, stream>>>(h, dr1w, dr1b, q, NTOK, 128, 256);

    // ================= encoder 2 (d=128, ff=512, hd=16) =================
    gemm_bias_kernel<0><<<dim3(2,  MB), blk, 0, stream>>>(q, qw2, qb2, k, NTOK, 128, 128);
    gemm_bias_kernel<0><<<dim3(2,  MB), blk, 0, stream>>>(q, kw2, kb2, v, NTOK, 128, 128);
    gemm_bias_kernel<0><<<dim3(2,  MB), blk, 0, stream>>>(q, vw2, vb2, o, NTOK, 128, 128);
    flash_kernel<16><<<dim3(SEQ / 256, 64), blk, 0, stream>>>(k, v, o, big);
    gemm_bias_kernel<0><<<dim3(2,  MB), blk, 0, stream>>>(big, ow2, ob2, k, NTOK, 128, 128);
    ln_residual_kernel<128><<<NTOK / 4, blk, 0, stream>>>(k, q, ln1g2, ln1b2, q);
    gemm_bias_kernel<1><<<dim3(8,  MB), blk, 0, stream>>>(q, f1w2, f1b2, big, NTOK, 512, 128);
    gemm_bias_kernel<0><<<dim3(2,  MB), blk, 0, stream>>>(big, f2w2, f2b2, k, NTOK, 128, 512);
    ln_residual_kernel<128><<<NTOK / 4, blk, 0, stream>>>(k, q, ln2g2, ln2b2, q);

    // ---- 128 -> 64, pool, head ----
    gemm_bias_kernel<0><<<dim3(1,  MB), blk, 0, stream>>>(q, dr2w, dr2b, k, NTOK, 64, 128);
    maxpool_kernel<<<BATCH, blk, 0, stream>>>(k, v);            // v[0..511] = pooled [8,64]
    head_kernel<<<1, blk, 0, stream>>>(v, dr3w, dr3b, dr4w, dr4b, (float*)d_out);
}

// Round 2
// 1186.287 us; speedup vs baseline: 1.9670x; 1.9670x over previous
//
#include <hip/hip_runtime.h>
#include <hip/hip_bf16.h>
#include <math.h>

#define SEQ  2048
#define BATCH 8
#define NTOK (SEQ*BATCH)   // 16384 tokens

typedef __attribute__((ext_vector_type(8))) short short8v;
typedef __attribute__((ext_vector_type(4))) float f32x4;

__device__ __forceinline__ unsigned short f2bf(float f) {
    __hip_bfloat16 h = __float2bfloat16(f);
    return *reinterpret_cast<unsigned short*>(&h);
}

// ---------------------------------------------------------------------------
// 1) h = x + positional encoding
// ---------------------------------------------------------------------------
__global__ __launch_bounds__(256) void add_pe_kernel(const float* __restrict__ x,
                                                     float* __restrict__ h) {
    int idx = blockIdx.x * 256 + threadIdx.x;     // over SEQ*256
    int s = idx >> 8;
    int d = idx & 255;
    float p   = powf(10000.0f, (float)d * (1.0f / 256.0f));
    float ang = (float)s / p;
    float pe  = (d & 1) ? cosf(ang) : sinf(ang);
    #pragma unroll
    for (int b = 0; b < BATCH; ++b) {
        size_t g = ((size_t)(b * SEQ + s) << 8) + d;
        h[g] = x[g] + pe;
    }
}

// ---------------------------------------------------------------------------
// 2) fp32 tiled GEMM (unchanged this round)
// ---------------------------------------------------------------------------
template<int RELU>
__global__ __launch_bounds__(256) void gemm_bias_kernel(
    const float* __restrict__ A, const float* __restrict__ W,
    const float* __restrict__ bias, float* __restrict__ C,
    int M, int N, int K)
{
    __shared__ float As[16][72];
    __shared__ float Bs[16][72];
    const int bm  = blockIdx.y * 64;
    const int bn  = blockIdx.x * 64;
    const int tid = threadIdx.x;
    const int tx  = tid & 15, ty = tid >> 4;

    float acc[4][4] = {{0.f}};

    for (int k0 = 0; k0 < K; k0 += 16) {
        #pragma unroll
        for (int i = 0; i < 4; ++i) {
            int f = tid + 256 * i;
            int row = f >> 4, kk = f & 15;
            As[kk][row] = A[(size_t)(bm + row) * K + k0 + kk];
        }
        #pragma unroll
        for (int i = 0; i < 4; ++i) {
            int f = tid + 256 * i;
            int kk = f >> 6, n = f & 63;
            Bs[kk][n] = W[(size_t)(k0 + kk) * N + bn + n];
        }
        __syncthreads();
        #pragma unroll
        for (int kk = 0; kk < 16; ++kk) {
            float4 a4 = *(const float4*)&As[kk][ty * 4];
            float4 b4 = *(const float4*)&Bs[kk][tx * 4];
            float av[4] = {a4.x, a4.y, a4.z, a4.w};
            float bv[4] = {b4.x, b4.y, b4.z, b4.w};
            #pragma unroll
            for (int i = 0; i < 4; ++i)
                #pragma unroll
                for (int j = 0; j < 4; ++j)
                    acc[i][j] = fmaf(av[i], bv[j], acc[i][j]);
        }
        __syncthreads();
    }

    float4 b4 = *(const float4*)&bias[bn + tx * 4];
    float bv[4] = {b4.x, b4.y, b4.z, b4.w};
    #pragma unroll
    for (int i = 0; i < 4; ++i) {
        int row = bm + ty * 4 + i;
        float4 o;
        float v0 = acc[i][0] + bv[0];
        float v1 = acc[i][1] + bv[1];
        float v2 = acc[i][2] + bv[2];
        float v3 = acc[i][3] + bv[3];
        if (RELU) {
            v0 = fmaxf(v0, 0.f); v1 = fmaxf(v1, 0.f);
            v2 = fmaxf(v2, 0.f); v3 = fmaxf(v3, 0.f);
        }
        o.x = v0; o.y = v1; o.z = v2; o.w = v3;
        *(float4*)&C[(size_t)row * N + bn + tx * 4] = o;
    }
}

// ---------------------------------------------------------------------------
// 3) LayerNorm(a + r) * g + b
// ---------------------------------------------------------------------------
template<int D>
__global__ __launch_bounds__(256) void ln_residual_kernel(
    const float* __restrict__ a, const float* __restrict__ r,
    const float* __restrict__ g, const float* __restrict__ bb,
    float* __restrict__ out)
{
    const int N = D >> 6;
    int wave = threadIdx.x >> 6;
    int lane = threadIdx.x & 63;
    size_t token = (size_t)blockIdx.x * 4 + wave;
    const float* ar = a + token * D;
    const float* rr = r + token * D;
    float*      orow = out + token * D;

    float xv[N];
    float s = 0.f;
    #pragma unroll
    for (int i = 0; i < N; ++i) {
        int d = lane + (i << 6);
        xv[i] = ar[d] + rr[d];
        s += xv[i];
    }
    #pragma unroll
    for (int off = 1; off < 64; off <<= 1) s += __shfl_xor(s, off);
    float mean = s * (1.0f / D);
    float vs = 0.f;
    #pragma unroll
    for (int i = 0; i < N; ++i) { float d0 = xv[i] - mean; vs += d0 * d0; }
    #pragma unroll
    for (int off = 1; off < 64; off <<= 1) vs += __shfl_xor(vs, off);
    float inv = 1.0f / sqrtf(vs * (1.0f / D) + 1e-5f);
    #pragma unroll
    for (int i = 0; i < N; ++i) {
        int d = lane + (i << 6);
        orow[d] = (xv[i] - mean) * inv * g[d] + bb[d];
    }
}

// ---------------------------------------------------------------------------
// 4) bf16-MFMA flash attention.  fp32 in/out, fp32 softmax state.
//    Layout [B, S, 8*HD]; HD = 32 (enc1) or 16 (enc2, k-dim zero-padded).
//    Block: 4 waves x 32 q-rows = 128 q rows.  Key tiles of 64.
//    mfma_f32_16x16x32_bf16 layouts:
//      A: row = lane%16, k = 8*(lane/16)+i (8 contiguous)
//      B: col = lane%16, k = 8*(lane/16)+i
//      C/D: col = lane%16, row = 4*(lane/16)+reg        [guide m89-verified]
//    P is written packed: storage position for key k (0..63):
//      pos = 32*(k>>5) + 2*(k&15) + ((k>>4)&1)
//    so each C-frag pair (kh, kh+1) packs to one b32, and A-frag reads are
//    contiguous b128.  V is staged transposed with the SAME permutation, so
//    sum over permuted k == sum over k.
// ---------------------------------------------------------------------------
template<int HD>
__global__ __launch_bounds__(256) void flash_mfma_kernel(
    const float* __restrict__ Qg, const float* __restrict__ Kg,
    const float* __restrict__ Vg, float* __restrict__ Og)
{
    constexpr int D    = 8 * HD;
    constexpr int NDH  = HD / 16;        // d-halves per head: 2 or 1
    constexpr int KSTR = 40;             // ushorts per Ks row (32ch + pad)
    constexpr int PSTR = 72;             // ushorts per Vt/P row (64 + pad)
    const float qs = (HD == 32) ? 0.25503488f : 0.36067376f;  // log2e/sqrt(hd)

    __shared__ unsigned short Ks[64 * KSTR];
    __shared__ unsigned short Vt[(NDH * 16) * PSTR];
    __shared__ unsigned short Pb[4 * 16 * PSTR];

    const int tid  = threadIdx.x;
    const int w    = tid >> 6;
    const int lane = tid & 63;
    const int c    = lane & 15;
    const int g    = lane >> 4;

    const int bh = blockIdx.y;
    const int b  = bh >> 3, hh = bh & 7;
    const size_t base = (size_t)b * SEQ * D + (size_t)hh * HD;
    const int qbase = blockIdx.x * 128;

    // ---- Q fragments (held for the whole kernel) ----
    short8v qf[2];
    #pragma unroll
    for (int qb = 0; qb < 2; ++qb) {
        short8v v;
        if (HD == 16 && g >= 2) {
            #pragma unroll
            for (int i = 0; i < 8; ++i) v[i] = 0;
        } else {
            int qrow = qbase + w * 32 + qb * 16 + c;
            const float* p = Qg + base + (size_t)qrow * D + 8 * g;
            float4 a  = *(const float4*)p;
            float4 b2 = *(const float4*)(p + 4);
            v[0] = (short)f2bf(a.x  * qs); v[1] = (short)f2bf(a.y  * qs);
            v[2] = (short)f2bf(a.z  * qs); v[3] = (short)f2bf(a.w  * qs);
            v[4] = (short)f2bf(b2.x * qs); v[5] = (short)f2bf(b2.y * qs);
            v[6] = (short)f2bf(b2.z * qs); v[7] = (short)f2bf(b2.w * qs);
        }
        qf[qb] = v;
    }

    f32x4 oacc[2][NDH];
    float mreg[2][4], lreg[2][4];
    #pragma unroll
    for (int qb = 0; qb < 2; ++qb) {
        #pragma unroll
        for (int dh = 0; dh < NDH; ++dh) oacc[qb][dh] = (f32x4){0.f, 0.f, 0.f, 0.f};
        #pragma unroll
        for (int i = 0; i < 4; ++i) { mreg[qb][i] = -INFINITY; lreg[qb][i] = 0.f; }
    }

    const int skey = tid >> 2;            // 0..63
    const int sch  = (tid & 3) * 8;       // 0,8,16,24
    const int spos = ((skey >> 5) << 5) + 2 * (skey & 15) + ((skey >> 4) & 1);

    for (int kt = 0; kt < SEQ; kt += 64) {
        __syncthreads();
        // ---- stage K tile ----
        {
            short8v kv;
            if (HD == 16 && sch >= 16) {
                #pragma unroll
                for (int i = 0; i < 8; ++i) kv[i] = 0;
            } else {
                const float* p = Kg + base + (size_t)(kt + skey) * D + sch;
                float4 a  = *(const float4*)p;
                float4 b2 = *(const float4*)(p + 4);
                kv[0] = (short)f2bf(a.x);  kv[1] = (short)f2bf(a.y);
                kv[2] = (short)f2bf(a.z);  kv[3] = (short)f2bf(a.w);
                kv[4] = (short)f2bf(b2.x); kv[5] = (short)f2bf(b2.y);
                kv[6] = (short)f2bf(b2.z); kv[7] = (short)f2bf(b2.w);
            }
            *(short8v*)&Ks[skey * KSTR + sch] = kv;
        }
        // ---- stage V tile (transposed + permuted) ----
        if (!(HD == 16 && sch >= 16)) {
            const float* p = Vg + base + (size_t)(kt + skey) * D + sch;
            float4 a  = *(const float4*)p;
            float4 b2 = *(const float4*)(p + 4);
            float vv[8] = {a.x, a.y, a.z, a.w, b2.x, b2.y, b2.z, b2.w};
            #pragma unroll
            for (int i = 0; i < 8; ++i)
                Vt[(sch + i) * PSTR + spos] = f2bf(vv[i]);
        }
        __syncthreads();

        // ---- K / V fragments (shared across both q-blocks) ----
        short8v kf[4];
        #pragma unroll
        for (int kh = 0; kh < 4; ++kh)
            kf[kh] = *(const short8v*)&Ks[(16 * kh + c) * KSTR + 8 * g];
        short8v vf[NDH][2];
        #pragma unroll
        for (int dh = 0; dh < NDH; ++dh)
            #pragma unroll
            for (int kc = 0; kc < 2; ++kc)
                vf[dh][kc] = *(const short8v*)&Vt[(16 * dh + c) * PSTR + 32 * kc + 8 * g];

        #pragma unroll
        for (int qb = 0; qb < 2; ++qb) {
            // QK^T : S[16q x 64k]
            f32x4 s[4];
            #pragma unroll
            for (int kh = 0; kh < 4; ++kh)
                s[kh] = __builtin_amdgcn_mfma_f32_16x16x32_bf16(
                            qf[qb], kf[kh], (f32x4){0.f, 0.f, 0.f, 0.f}, 0, 0, 0);

            // online softmax (rows 4g+i live on lanes 16g..16g+15)
            unsigned* Pu = (unsigned*)Pb;
            #pragma unroll
            for (int i = 0; i < 4; ++i) {
                float tm = fmaxf(fmaxf(s[0][i], s[1][i]), fmaxf(s[2][i], s[3][i]));
                tm = fmaxf(tm, __shfl_xor(tm, 1));
                tm = fmaxf(tm, __shfl_xor(tm, 2));
                tm = fmaxf(tm, __shfl_xor(tm, 4));
                tm = fmaxf(tm, __shfl_xor(tm, 8));
                float mo = mreg[qb][i];
                float mn = fmaxf(mo, tm);
                float resc = exp2f(mo - mn);      // first tile: exp2(-inf)=0
                mreg[qb][i] = mn;
                float p0 = exp2f(s[0][i] - mn);
                float p1 = exp2f(s[1][i] - mn);
                float p2 = exp2f(s[2][i] - mn);
                float p3 = exp2f(s[3][i] - mn);
                lreg[qb][i] = lreg[qb][i] * resc + (p0 + p1 + p2 + p3);
                #pragma unroll
                for (int dh = 0; dh < NDH; ++dh) oacc[qb][dh][i] *= resc;
                int row = w * 16 + 4 * g + i;
                Pu[row * (PSTR / 2) + c]      = (unsigned)f2bf(p0) | ((unsigned)f2bf(p1) << 16);
                Pu[row * (PSTR / 2) + 16 + c] = (unsigned)f2bf(p2) | ((unsigned)f2bf(p3) << 16);
            }

            // PV : O[16q x HD] += P(16x64) @ V(64xHD)   (k-dim = permuted pos)
            short8v pf0 = *(const short8v*)&Pb[(w * 16 + c) * PSTR + 8 * g];
            short8v pf1 = *(const short8v*)&Pb[(w * 16 + c) * PSTR + 32 + 8 * g];
            #pragma unroll
            for (int dh = 0; dh < NDH; ++dh) {
                oacc[qb][dh] = __builtin_amdgcn_mfma_f32_16x16x32_bf16(
                                   pf0, vf[dh][0], oacc[qb][dh], 0, 0, 0);
                oacc[qb][dh] = __builtin_amdgcn_mfma_f32_16x16x32_bf16(
                                   pf1, vf[dh][1], oacc[qb][dh], 0, 0, 0);
            }
        }
    }

    // ---- epilogue: O = acc / l ----
    #pragma unroll
    for (int qb = 0; qb < 2; ++qb) {
        #pragma unroll
        for (int i = 0; i < 4; ++i) {
            float li = lreg[qb][i];
            li += __shfl_xor(li, 1);
            li += __shfl_xor(li, 2);
            li += __shfl_xor(li, 4);
            li += __shfl_xor(li, 8);
            float inv = 1.0f / li;
            int qrow = qbase + w * 32 + qb * 16 + 4 * g + i;
            #pragma unroll
            for (int dh = 0; dh < NDH; ++dh)
                Og[base + (size_t)qrow * D + 16 * dh + c] = oacc[qb][dh][i] * inv;
        }
    }
}

// ---------------------------------------------------------------------------
// 5) max over sequence dim
// ---------------------------------------------------------------------------
__global__ __launch_bounds__(256) void maxpool_kernel(const float* __restrict__ in,
                                                      float* __restrict__ out) {
    __shared__ float red[4][64];
    int b = blockIdx.x, d = threadIdx.x & 63, st = threadIdx.x >> 6;
    float m = -INFINITY;
    for (int s = st * (SEQ / 4); s < (st + 1) * (SEQ / 4); ++s)
        m = fmaxf(m, in[((size_t)b * SEQ + s) * 64 + d]);
    red[st][d] = m;
    __syncthreads();
    if (st == 0) {
        m = fmaxf(fmaxf(red[0][d], red[1][d]), fmaxf(red[2][d], red[3][d]));
        out[b * 64 + d] = m;
    }
}

// ---------------------------------------------------------------------------
// 6) head
// ---------------------------------------------------------------------------
__global__ __launch_bounds__(256) void head_kernel(
    const float* __restrict__ pooled,
    const float* __restrict__ w3, const float* __restrict__ b3,
    const float* __restrict__ w4, const float* __restrict__ b4,
    float* __restrict__ out)
{
    __shared__ float t[8][32];
    int tid = threadIdx.x;
    {
        int b = tid >> 5, j = tid & 31;
        float s = b3[j];
        #pragma unroll
        for (int k = 0; k < 64; ++k) s = fmaf(pooled[b * 64 + k], w3[k * 32 + j], s);
        t[b][j] = s;
    }
    __syncthreads();
    if (tid < 8 * 14) {
        int b = tid / 14, j = tid % 14;
        float s = b4[j];
        #pragma unroll
        for (int k = 0; k < 32; ++k) s = fmaf(t[b][k], w4[k * 14 + j], s);
        out[b * 14 + j] = s;
    }
}

// ---------------------------------------------------------------------------
extern "C" void kernel_launch(void* const* d_in, const int* in_sizes, int n_in,
                              void* d_out, int out_size, void* d_ws, size_t ws_size,
                              hipStream_t stream) {
    const float* x     = (const float*)d_in[0];
    const float* qw1   = (const float*)d_in[1];
    const float* qb1   = (const float*)d_in[2];
    const float* kw1   = (const float*)d_in[3];
    const float* kb1   = (const float*)d_in[4];
    const float* vw1   = (const float*)d_in[5];
    const float* vb1   = (const float*)d_in[6];
    const float* ow1   = (const float*)d_in[7];
    const float* ob1   = (const float*)d_in[8];
    const float* f1w1  = (const float*)d_in[9];
    const float* f1b1  = (const float*)d_in[10];
    const float* f2w1  = (const float*)d_in[11];
    const float* f2b1  = (const float*)d_in[12];
    const float* ln1g1 = (const float*)d_in[13];
    const float* ln1b1 = (const float*)d_in[14];
    const float* ln2g1 = (const float*)d_in[15];
    const float* ln2b1 = (const float*)d_in[16];
    const float* qw2   = (const float*)d_in[17];
    const float* qb2   = (const float*)d_in[18];
    const float* kw2   = (const float*)d_in[19];
    const float* kb2   = (const float*)d_in[20];
    const float* vw2   = (const float*)d_in[21];
    const float* vb2   = (const float*)d_in[22];
    const float* ow2   = (const float*)d_in[23];
    const float* ob2   = (const float*)d_in[24];
    const float* f1w2  = (const float*)d_in[25];
    const float* f1b2  = (const float*)d_in[26];
    const float* f2w2  = (const float*)d_in[27];
    const float* f2b2  = (const float*)d_in[28];
    const float* ln1g2 = (const float*)d_in[29];
    const float* ln1b2 = (const float*)d_in[30];
    const float* ln2g2 = (const float*)d_in[31];
    const float* ln2b2 = (const float*)d_in[32];
    const float* dr1w  = (const float*)d_in[33];
    const float* dr1b  = (const float*)d_in[34];
    const float* dr2w  = (const float*)d_in[35];
    const float* dr2b  = (const float*)d_in[36];
    const float* dr3w  = (const float*)d_in[37];
    const float* dr3b  = (const float*)d_in[38];
    const float* dr4w  = (const float*)d_in[39];
    const float* dr4b  = (const float*)d_in[40];

    const size_t T = NTOK;
    float* ws  = (float*)d_ws;
    float* h   = ws;                 // [T,256]
    float* q   = h   + T * 256;      // [T,256]
    float* k   = q   + T * 256;      // [T,256]
    float* v   = k   + T * 256;      // [T,256]
    float* o   = v   + T * 256;      // [T,256]
    float* big = o   + T * 256;      // [T,1024]

    const dim3 blk(256);
    const int MB = NTOK / 64;        // 256 M-tiles

    add_pe_kernel<<<SEQ * 256 / 256, blk, 0, stream>>>(x, h);

    // ================= encoder 1 (d=256, ff=1024, hd=32) =================
    gemm_bias_kernel<0><<<dim3(4,  MB), blk, 0, stream>>>(h, qw1, qb1, q, NTOK, 256, 256);
    gemm_bias_kernel<0><<<dim3(4,  MB), blk, 0, stream>>>(h, kw1, kb1, k, NTOK, 256, 256);
    gemm_bias_kernel<0><<<dim3(4,  MB), blk, 0, stream>>>(h, vw1, vb1, v, NTOK, 256, 256);
    flash_mfma_kernel<32><<<dim3(SEQ / 128, 64), blk, 0, stream>>>(q, k, v, o);
    gemm_bias_kernel<0><<<dim3(4,  MB), blk, 0, stream>>>(o, ow1, ob1, big, NTOK, 256, 256);
    ln_residual_kernel<256><<<NTOK / 4, blk, 0, stream>>>(big, h, ln1g1, ln1b1, h);
    gemm_bias_kernel<1><<<dim3(16, MB), blk, 0, stream>>>(h, f1w1, f1b1, big, NTOK, 1024, 256);
    gemm_bias_kernel<0><<<dim3(4,  MB), blk, 0, stream>>>(big, f2w1, f2b1, q, NTOK, 256, 1024);
    ln_residual_kernel<256><<<NTOK / 4, blk, 0, stream>>>(q, h, ln2g1, ln2b1, h);

    // ---- 256 -> 128 ----
    gemm_bias_kernel<0><<<dim3(2,  MB), blk, 0, stream>>>(h, dr1w, dr1b, q, NTOK, 128, 256);

    // ================= encoder 2 (d=128, ff=512, hd=16) =================
    gemm_bias_kernel<0><<<dim3(2,  MB), blk, 0, stream>>>(q, qw2, qb2, k, NTOK, 128, 128);
    gemm_bias_kernel<0><<<dim3(2,  MB), blk, 0, stream>>>(q, kw2, kb2, v, NTOK, 128, 128);
    gemm_bias_kernel<0><<<dim3(2,  MB), blk, 0, stream>>>(q, vw2, vb2, o, NTOK, 128, 128);
    flash_mfma_kernel<16><<<dim3(SEQ / 128, 64), blk, 0, stream>>>(k, v, o, big);
    gemm_bias_kernel<0><<<dim3(2,  MB), blk, 0, stream>>>(big, ow2, ob2, k, NTOK, 128, 128);
    ln_residual_kernel<128><<<NTOK / 4, blk, 0, stream>>>(k, q, ln1g2, ln1b2, q);
    gemm_bias_kernel<1><<<dim3(8,  MB), blk, 0, stream>>>(q, f1w2, f1b2, big, NTOK, 512, 128);
    gemm_bias_kernel<0><<<dim3(2,  MB), blk, 0, stream>>>(big, f2w2, f2b2, k, NTOK, 128, 512);
    ln_residual_kernel<128><<<NTOK / 4, blk, 0, stream>>>(k, q, ln2g2, ln2b2, q);

    // ---- 128 -> 64, pool, head ----
    gemm_bias_kernel<0><<<dim3(1,  MB), blk, 0, stream>>>(q, dr2w, dr2b, k, NTOK, 64, 128);
    maxpool_kernel<<<BATCH, blk, 0, stream>>>(k, v);
    head_kernel<<<1, blk, 0, stream>>>(v, dr3w, dr3b, dr4w, dr4b, (float*)d_out);
}

// Round 3
// 599.519 us; speedup vs baseline: 3.8922x; 1.9787x over previous
//
#include <hip/hip_runtime.h>
#include <hip/hip_bf16.h>
#include <math.h>

#define SEQ  2048
#define BATCH 8
#define NTOK (SEQ*BATCH)   // 16384 tokens

typedef __attribute__((ext_vector_type(8))) short short8v;
typedef __attribute__((ext_vector_type(4))) float f32x4;
typedef unsigned short u16;

__device__ __forceinline__ u16 f2bf(float f) {
    __hip_bfloat16 h = __float2bfloat16(f);
    return *reinterpret_cast<u16*>(&h);
}

// ---------------------------------------------------------------------------
// 0a) weight convert + transpose:  W[K][N] fp32  ->  Wt[N][K] bf16 (xscale)
//     13 sub-weights into one arena; 64x64 LDS tile transpose per block.
// ---------------------------------------------------------------------------
struct WDescs {
    const float* src[13];
    int K[13];
    int N[13];
    long dst[13];
    float scale[13];
    int tstart[14];
};

__global__ __launch_bounds__(256) void convert_w_kernel(WDescs d, u16* __restrict__ WA) {
    __shared__ float tile[64][65];
    int blk = blockIdx.x;
    int di = 0;
    while (di < 12 && blk >= d.tstart[di + 1]) ++di;
    int t  = blk - d.tstart[di];
    int K  = d.K[di], N = d.N[di];
    int tn = N >> 6;
    int k0 = (t / tn) << 6, n0 = (t % tn) << 6;
    const float* src = d.src[di];
    float sc = d.scale[di];
    int tid = threadIdx.x;
    #pragma unroll
    for (int i = 0; i < 16; ++i) {
        int id = i * 256 + tid;
        int kk = id >> 6, nn = id & 63;
        tile[kk][nn] = src[(size_t)(k0 + kk) * N + n0 + nn];
    }
    __syncthreads();
    u16* dst = WA + d.dst[di];
    #pragma unroll
    for (int i = 0; i < 16; ++i) {
        int id = i * 256 + tid;
        int nn = id >> 6, kk = id & 63;
        dst[(size_t)(n0 + nn) * K + k0 + kk] = f2bf(tile[kk][nn] * sc);
    }
}

// 0b) combined qkv bias arenas (q-part scaled by log2e/sqrt(hd))
__global__ __launch_bounds__(256) void convert_bias_kernel(
    const float* qb1, const float* kb1, const float* vb1,
    const float* qb2, const float* kb2, const float* vb2,
    float* __restrict__ BA, float qs1, float qs2)
{
    int t = blockIdx.x * 256 + threadIdx.x;
    if      (t < 256)  BA[t] = qb1[t] * qs1;
    else if (t < 512)  BA[t] = kb1[t - 256];
    else if (t < 768)  BA[t] = vb1[t - 512];
    else if (t < 896)  BA[t] = qb2[t - 768] * qs2;
    else if (t < 1024) BA[t] = kb2[t - 896];
    else if (t < 1152) BA[t] = vb2[t - 1024];
}

// ---------------------------------------------------------------------------
// 1) h = x + positional encoding  ->  fp32 residual + bf16 GEMM input
// ---------------------------------------------------------------------------
__global__ __launch_bounds__(256) void add_pe_kernel(const float* __restrict__ x,
                                                     float* __restrict__ h,
                                                     u16* __restrict__ hb) {
    int idx = blockIdx.x * 256 + threadIdx.x;     // over SEQ*256
    int s = idx >> 8;
    int d = idx & 255;
    float p   = powf(10000.0f, (float)d * (1.0f / 256.0f));
    float ang = (float)s / p;
    float pe  = (d & 1) ? cosf(ang) : sinf(ang);
    #pragma unroll
    for (int b = 0; b < BATCH; ++b) {
        size_t g = ((size_t)(b * SEQ + s) << 8) + d;
        float v = x[g] + pe;
        h[g]  = v;
        hb[g] = f2bf(v);
    }
}

// ---------------------------------------------------------------------------
// 2) bf16 MFMA GEMM:  C[M,N] = A[M,K](bf16) @ Wt[N,K](bf16)^T + bias(f32)
//    128x128 tile, BK=64, 4 waves (2x2), 4x4 16x16x32 frags per wave,
//    double-buffered LDS, XOR-swizzled 16B blocks for conflict-free b128.
// ---------------------------------------------------------------------------
template<int RELU, int WF32, int WBF16>
__global__ __launch_bounds__(256) void gemm_bf16_kernel(
    const u16* __restrict__ A, const u16* __restrict__ Bt,
    const float* __restrict__ bias, float* __restrict__ Cf,
    u16* __restrict__ Cb, int N, int K)
{
    __shared__ u16 As[2][128 * 64];
    __shared__ u16 Bs[2][128 * 64];
    const int tid  = threadIdx.x;
    const int lane = tid & 63;
    const int c    = lane & 15, g = lane >> 4;
    const int w    = tid >> 6;
    const int wr   = w >> 1, wc = w & 1;
    const size_t bm = (size_t)blockIdx.y * 128;
    const size_t bn = (size_t)blockIdx.x * 128;

    f32x4 acc[4][4];
    #pragma unroll
    for (int i = 0; i < 4; ++i)
        #pragma unroll
        for (int j = 0; j < 4; ++j) acc[i][j] = (f32x4){0.f, 0.f, 0.f, 0.f};

    auto stage = [&](int buf, int t) {
        #pragma unroll
        for (int j = 0; j < 4; ++j) {
            int cid = j * 256 + tid;
            int row = cid >> 3, blk = cid & 7;
            int lofs = row * 64 + ((blk ^ (row & 7)) * 8);
            short8v av = *(const short8v*)&A[(bm + row) * K + t * 64 + blk * 8];
            *(short8v*)&As[buf][lofs] = av;
            short8v bv = *(const short8v*)&Bt[(bn + row) * K + t * 64 + blk * 8];
            *(short8v*)&Bs[buf][lofs] = bv;
        }
    };

    const int nt = K >> 6;
    stage(0, 0);
    __syncthreads();
    for (int t = 0; t < nt; ++t) {
        if (t + 1 < nt) stage((t + 1) & 1, t + 1);
        const int bfi = t & 1;
        #pragma unroll
        for (int ks2 = 0; ks2 < 2; ++ks2) {
            short8v af[4], bfr[4];
            #pragma unroll
            for (int am = 0; am < 4; ++am) {
                int r = wr * 64 + am * 16 + c;
                af[am] = *(const short8v*)&As[bfi][r * 64 + (((ks2 * 4 + g) ^ (r & 7)) * 8)];
            }
            #pragma unroll
            for (int bn_ = 0; bn_ < 4; ++bn_) {
                int r = wc * 64 + bn_ * 16 + c;
                bfr[bn_] = *(const short8v*)&Bs[bfi][r * 64 + (((ks2 * 4 + g) ^ (r & 7)) * 8)];
            }
            #pragma unroll
            for (int am = 0; am < 4; ++am)
                #pragma unroll
                for (int bn_ = 0; bn_ < 4; ++bn_)
                    acc[am][bn_] = __builtin_amdgcn_mfma_f32_16x16x32_bf16(
                                       af[am], bfr[bn_], acc[am][bn_], 0, 0, 0);
        }
        __syncthreads();
    }

    float bv[4];
    #pragma unroll
    for (int bn_ = 0; bn_ < 4; ++bn_) bv[bn_] = bias[bn + wc * 64 + bn_ * 16 + c];
    #pragma unroll
    for (int am = 0; am < 4; ++am) {
        #pragma unroll
        for (int bn_ = 0; bn_ < 4; ++bn_) {
            #pragma unroll
            for (int i = 0; i < 4; ++i) {
                size_t row = bm + wr * 64 + am * 16 + 4 * g + i;
                size_t col = bn + wc * 64 + bn_ * 16 + c;
                float v = acc[am][bn_][i] + bv[bn_];
                if (RELU) v = fmaxf(v, 0.f);
                if (WF32)  Cf[row * N + col] = v;
                if (WBF16) Cb[row * N + col] = f2bf(v);
            }
        }
    }
}

// ---------------------------------------------------------------------------
// 3) fp32 tiled GEMM (kept only for dr2, N=64)
// ---------------------------------------------------------------------------
template<int RELU>
__global__ __launch_bounds__(256) void gemm_bias_kernel(
    const float* __restrict__ A, const float* __restrict__ W,
    const float* __restrict__ bias, float* __restrict__ C,
    int M, int N, int K)
{
    __shared__ float As[16][72];
    __shared__ float Bs[16][72];
    const int bm  = blockIdx.y * 64;
    const int bn  = blockIdx.x * 64;
    const int tid = threadIdx.x;
    const int tx  = tid & 15, ty = tid >> 4;

    float acc[4][4] = {{0.f}};

    for (int k0 = 0; k0 < K; k0 += 16) {
        #pragma unroll
        for (int i = 0; i < 4; ++i) {
            int f = tid + 256 * i;
            int row = f >> 4, kk = f & 15;
            As[kk][row] = A[(size_t)(bm + row) * K + k0 + kk];
        }
        #pragma unroll
        for (int i = 0; i < 4; ++i) {
            int f = tid + 256 * i;
            int kk = f >> 6, n = f & 63;
            Bs[kk][n] = W[(size_t)(k0 + kk) * N + bn + n];
        }
        __syncthreads();
        #pragma unroll
        for (int kk = 0; kk < 16; ++kk) {
            float4 a4 = *(const float4*)&As[kk][ty * 4];
            float4 b4 = *(const float4*)&Bs[kk][tx * 4];
            float av[4] = {a4.x, a4.y, a4.z, a4.w};
            float bw[4] = {b4.x, b4.y, b4.z, b4.w};
            #pragma unroll
            for (int i = 0; i < 4; ++i)
                #pragma unroll
                for (int j = 0; j < 4; ++j)
                    acc[i][j] = fmaf(av[i], bw[j], acc[i][j]);
        }
        __syncthreads();
    }

    float4 b4 = *(const float4*)&bias[bn + tx * 4];
    float bw[4] = {b4.x, b4.y, b4.z, b4.w};
    #pragma unroll
    for (int i = 0; i < 4; ++i) {
        int row = bm + ty * 4 + i;
        float4 o;
        float v0 = acc[i][0] + bw[0];
        float v1 = acc[i][1] + bw[1];
        float v2 = acc[i][2] + bw[2];
        float v3 = acc[i][3] + bw[3];
        if (RELU) {
            v0 = fmaxf(v0, 0.f); v1 = fmaxf(v1, 0.f);
            v2 = fmaxf(v2, 0.f); v3 = fmaxf(v3, 0.f);
        }
        o.x = v0; o.y = v1; o.z = v2; o.w = v3;
        *(float4*)&C[(size_t)row * N + bn + tx * 4] = o;
    }
}

// ---------------------------------------------------------------------------
// 4) LayerNorm(a + r) * g + b  ->  fp32 (+ optional bf16)
// ---------------------------------------------------------------------------
template<int D, int WBF>
__global__ __launch_bounds__(256) void ln_residual_kernel(
    const float* __restrict__ a, const float* __restrict__ r,
    const float* __restrict__ g, const float* __restrict__ bb,
    float* __restrict__ out, u16* __restrict__ outb)
{
    const int N = D >> 6;
    int wave = threadIdx.x >> 6;
    int lane = threadIdx.x & 63;
    size_t token = (size_t)blockIdx.x * 4 + wave;
    const float* ar = a + token * D;
    const float* rr = r + token * D;

    float xv[N];
    float s = 0.f;
    #pragma unroll
    for (int i = 0; i < N; ++i) {
        int d = lane + (i << 6);
        xv[i] = ar[d] + rr[d];
        s += xv[i];
    }
    #pragma unroll
    for (int off = 1; off < 64; off <<= 1) s += __shfl_xor(s, off);
    float mean = s * (1.0f / D);
    float vs = 0.f;
    #pragma unroll
    for (int i = 0; i < N; ++i) { float d0 = xv[i] - mean; vs += d0 * d0; }
    #pragma unroll
    for (int off = 1; off < 64; off <<= 1) vs += __shfl_xor(vs, off);
    float inv = 1.0f / sqrtf(vs * (1.0f / D) + 1e-5f);
    #pragma unroll
    for (int i = 0; i < N; ++i) {
        int d = lane + (i << 6);
        float v = (xv[i] - mean) * inv * g[d] + bb[d];
        out[token * D + d] = v;
        if (WBF) outb[token * D + d] = f2bf(v);
    }
}

// ---------------------------------------------------------------------------
// 5) bf16-MFMA flash attention, packed QKV input [T, 3*D] bf16, bf16 out.
//    No running max: softmax is shift-invariant and |s| << exp2 range, so
//    p = exp2(s) directly (q pre-scaled by log2e/sqrt(hd) in the weights).
//    P/V use the permuted-key packing validated in round 2.
// ---------------------------------------------------------------------------
template<int HD>
__global__ __launch_bounds__(256) void flash_mfma_kernel(
    const u16* __restrict__ QKV, u16* __restrict__ Og)
{
    constexpr int D    = 8 * HD;
    constexpr int SD   = 3 * D;
    constexpr int NDH  = HD / 16;
    constexpr int KSTR = 40;
    constexpr int PSTR = 72;

    __shared__ u16 Ks[64 * KSTR];
    __shared__ u16 Vt[(NDH * 16) * PSTR];
    __shared__ u16 Pb[4 * 16 * PSTR];

    const int tid  = threadIdx.x;
    const int w    = tid >> 6;
    const int lane = tid & 63;
    const int c    = lane & 15;
    const int g    = lane >> 4;

    const int bh = blockIdx.y;
    const int b  = bh >> 3, hh = bh & 7;
    const size_t qvbase = (size_t)b * SEQ * SD + (size_t)hh * HD;
    const size_t obase  = (size_t)b * SEQ * D  + (size_t)hh * HD;
    const int qbase = blockIdx.x * 128;

    // Q fragments (pre-scaled in weights)
    short8v qf[2];
    #pragma unroll
    for (int qb = 0; qb < 2; ++qb) {
        if (HD == 16 && g >= 2) {
            short8v z;
            #pragma unroll
            for (int i = 0; i < 8; ++i) z[i] = 0;
            qf[qb] = z;
        } else {
            int qrow = qbase + w * 32 + qb * 16 + c;
            qf[qb] = *(const short8v*)&QKV[qvbase + (size_t)qrow * SD + 8 * g];
        }
    }

    f32x4 oacc[2][NDH];
    float lreg[2][4];
    #pragma unroll
    for (int qb = 0; qb < 2; ++qb) {
        #pragma unroll
        for (int dh = 0; dh < NDH; ++dh) oacc[qb][dh] = (f32x4){0.f, 0.f, 0.f, 0.f};
        #pragma unroll
        for (int i = 0; i < 4; ++i) lreg[qb][i] = 0.f;
    }

    const int skey = tid >> 2;            // 0..63
    const int sch  = (tid & 3) * 8;       // 0,8,16,24
    const int spos = ((skey >> 5) << 5) + 2 * (skey & 15) + ((skey >> 4) & 1);

    for (int kt = 0; kt < SEQ; kt += 64) {
        __syncthreads();
        // ---- stage K ----
        {
            short8v kv;
            if (HD == 16 && sch >= 16) {
                #pragma unroll
                for (int i = 0; i < 8; ++i) kv[i] = 0;
            } else {
                kv = *(const short8v*)&QKV[qvbase + (size_t)(kt + skey) * SD + D + sch];
            }
            *(short8v*)&Ks[skey * KSTR + sch] = kv;
        }
        // ---- stage V (transposed + key-permuted) ----
        if (!(HD == 16 && sch >= 16)) {
            short8v vv = *(const short8v*)&QKV[qvbase + (size_t)(kt + skey) * SD + 2 * D + sch];
            #pragma unroll
            for (int i = 0; i < 8; ++i)
                Vt[(sch + i) * PSTR + spos] = (u16)vv[i];
        }
        __syncthreads();

        short8v kf[4];
        #pragma unroll
        for (int kh = 0; kh < 4; ++kh)
            kf[kh] = *(const short8v*)&Ks[(16 * kh + c) * KSTR + 8 * g];
        short8v vf[NDH][2];
        #pragma unroll
        for (int dh = 0; dh < NDH; ++dh)
            #pragma unroll
            for (int kc = 0; kc < 2; ++kc)
                vf[dh][kc] = *(const short8v*)&Vt[(16 * dh + c) * PSTR + 32 * kc + 8 * g];

        #pragma unroll
        for (int qb = 0; qb < 2; ++qb) {
            f32x4 s[4];
            #pragma unroll
            for (int kh = 0; kh < 4; ++kh)
                s[kh] = __builtin_amdgcn_mfma_f32_16x16x32_bf16(
                            qf[qb], kf[kh], (f32x4){0.f, 0.f, 0.f, 0.f}, 0, 0, 0);

            unsigned* Pu = (unsigned*)Pb;
            #pragma unroll
            for (int i = 0; i < 4; ++i) {
                float p0 = exp2f(s[0][i]);
                float p1 = exp2f(s[1][i]);
                float p2 = exp2f(s[2][i]);
                float p3 = exp2f(s[3][i]);
                lreg[qb][i] += (p0 + p1) + (p2 + p3);
                int row = w * 16 + 4 * g + i;
                Pu[row * (PSTR / 2) + c]      = (unsigned)f2bf(p0) | ((unsigned)f2bf(p1) << 16);
                Pu[row * (PSTR / 2) + 16 + c] = (unsigned)f2bf(p2) | ((unsigned)f2bf(p3) << 16);
            }

            short8v pf0 = *(const short8v*)&Pb[(w * 16 + c) * PSTR + 8 * g];
            short8v pf1 = *(const short8v*)&Pb[(w * 16 + c) * PSTR + 32 + 8 * g];
            #pragma unroll
            for (int dh = 0; dh < NDH; ++dh) {
                oacc[qb][dh] = __builtin_amdgcn_mfma_f32_16x16x32_bf16(
                                   pf0, vf[dh][0], oacc[qb][dh], 0, 0, 0);
                oacc[qb][dh] = __builtin_amdgcn_mfma_f32_16x16x32_bf16(
                                   pf1, vf[dh][1], oacc[qb][dh], 0, 0, 0);
            }
        }
    }

    #pragma unroll
    for (int qb = 0; qb < 2; ++qb) {
        #pragma unroll
        for (int i = 0; i < 4; ++i) {
            float li = lreg[qb][i];
            li += __shfl_xor(li, 1);
            li += __shfl_xor(li, 2);
            li += __shfl_xor(li, 4);
            li += __shfl_xor(li, 8);
            float inv = 1.0f / li;
            int qrow = qbase + w * 32 + qb * 16 + 4 * g + i;
            #pragma unroll
            for (int dh = 0; dh < NDH; ++dh)
                Og[obase + (size_t)qrow * D + 16 * dh + c] = f2bf(oacc[qb][dh][i] * inv);
        }
    }
}

// ---------------------------------------------------------------------------
// 6) max over sequence dim:  in [B, S, 64] -> out [B, 64]
// ---------------------------------------------------------------------------
__global__ __launch_bounds__(256) void maxpool_kernel(const float* __restrict__ in,
                                                      float* __restrict__ out) {
    __shared__ float red[4][64];
    int b = blockIdx.x, d = threadIdx.x & 63, st = threadIdx.x >> 6;
    float m = -INFINITY;
    for (int s = st * (SEQ / 4); s < (st + 1) * (SEQ / 4); ++s)
        m = fmaxf(m, in[((size_t)b * SEQ + s) * 64 + d]);
    red[st][d] = m;
    __syncthreads();
    if (st == 0) {
        m = fmaxf(fmaxf(red[0][d], red[1][d]), fmaxf(red[2][d], red[3][d]));
        out[b * 64 + d] = m;
    }
}

// ---------------------------------------------------------------------------
// 7) head
// ---------------------------------------------------------------------------
__global__ __launch_bounds__(256) void head_kernel(
    const float* __restrict__ pooled,
    const float* __restrict__ w3, const float* __restrict__ b3,
    const float* __restrict__ w4, const float* __restrict__ b4,
    float* __restrict__ out)
{
    __shared__ float t[8][32];
    int tid = threadIdx.x;
    {
        int b = tid >> 5, j = tid & 31;
        float s = b3[j];
        #pragma unroll
        for (int k = 0; k < 64; ++k) s = fmaf(pooled[b * 64 + k], w3[k * 32 + j], s);
        t[b][j] = s;
    }
    __syncthreads();
    if (tid < 8 * 14) {
        int b = tid / 14, j = tid % 14;
        float s = b4[j];
        #pragma unroll
        for (int k = 0; k < 32; ++k) s = fmaf(t[b][k], w4[k * 14 + j], s);
        out[b * 14 + j] = s;
    }
}

// ---------------------------------------------------------------------------
extern "C" void kernel_launch(void* const* d_in, const int* in_sizes, int n_in,
                              void* d_out, int out_size, void* d_ws, size_t ws_size,
                              hipStream_t stream) {
    const float* x     = (const float*)d_in[0];
    const float* qw1   = (const float*)d_in[1];
    const float* qb1   = (const float*)d_in[2];
    const float* kw1   = (const float*)d_in[3];
    const float* kb1   = (const float*)d_in[4];
    const float* vw1   = (const float*)d_in[5];
    const float* vb1   = (const float*)d_in[6];
    const float* ow1   = (const float*)d_in[7];
    const float* ob1   = (const float*)d_in[8];
    const float* f1w1  = (const float*)d_in[9];
    const float* f1b1  = (const float*)d_in[10];
    const float* f2w1  = (const float*)d_in[11];
    const float* f2b1  = (const float*)d_in[12];
    const float* ln1g1 = (const float*)d_in[13];
    const float* ln1b1 = (const float*)d_in[14];
    const float* ln2g1 = (const float*)d_in[15];
    const float* ln2b1 = (const float*)d_in[16];
    const float* qw2   = (const float*)d_in[17];
    const float* qb2   = (const float*)d_in[18];
    const float* kw2   = (const float*)d_in[19];
    const float* kb2   = (const float*)d_in[20];
    const float* vw2   = (const float*)d_in[21];
    const float* vb2   = (const float*)d_in[22];
    const float* ow2   = (const float*)d_in[23];
    const float* ob2   = (const float*)d_in[24];
    const float* f1w2  = (const float*)d_in[25];
    const float* f1b2  = (const float*)d_in[26];
    const float* f2w2  = (const float*)d_in[27];
    const float* f2b2  = (const float*)d_in[28];
    const float* ln1g2 = (const float*)d_in[29];
    const float* ln1b2 = (const float*)d_in[30];
    const float* ln2g2 = (const float*)d_in[31];
    const float* ln2b2 = (const float*)d_in[32];
    const float* dr1w  = (const float*)d_in[33];
    const float* dr1b  = (const float*)d_in[34];
    const float* dr2w  = (const float*)d_in[35];
    const float* dr2b  = (const float*)d_in[36];
    const float* dr3w  = (const float*)d_in[37];
    const float* dr3b  = (const float*)d_in[38];
    const float* dr4w  = (const float*)d_in[39];
    const float* dr4b  = (const float*)d_in[40];

    const size_t T = NTOK;
    float* F1 = (float*)d_ws;            // [T,256] fp32 residual stream
    float* F2 = F1 + T * 256;            // [T,256] fp32 scratch
    u16*   E1 = (u16*)(F2 + T * 256);    // [T,256] bf16
    u16*   E2 = E1 + T * 256;            // [T,256] bf16
    u16*   E3 = E2 + T * 256;            // [T,256] bf16
    u16*   Dq = E3 + T * 256;            // [T,1024] bf16 (qkv-packed / ff scratch)
    u16*   WA = Dq + T * 1024;           // bf16 weight arena (1,015,808 used)
    float* BA = (float*)(WA + 1048576);  // combined qkv biases

    const float QS1 = 0.25503488f;       // log2e / sqrt(32)
    const float QS2 = 0.36067376f;       // log2e / sqrt(16)

    // weight descriptor table (src, K, N, dst_off, scale)
    WDescs wd;
    const float* srcs[13] = {qw1, kw1, vw1, ow1, f1w1, f2w1, dr1w,
                             qw2, kw2, vw2, ow2, f1w2, f2w2};
    int Ks_[13]  = {256, 256, 256, 256, 256, 1024, 256, 128, 128, 128, 128, 128, 512};
    int Ns_[13]  = {256, 256, 256, 256, 1024, 256, 128, 128, 128, 128, 128, 512, 128};
    long dsts[13] = {0, 65536, 131072, 196608, 262144, 524288, 786432,
                     819200, 835584, 851968, 868352, 884736, 950272};
    float scs[13] = {QS1, 1.f, 1.f, 1.f, 1.f, 1.f, 1.f, QS2, 1.f, 1.f, 1.f, 1.f, 1.f};
    int tst[14] = {0, 16, 32, 48, 64, 128, 192, 200, 204, 208, 212, 216, 232, 248};
    for (int i = 0; i < 13; ++i) {
        wd.src[i] = srcs[i]; wd.K[i] = Ks_[i]; wd.N[i] = Ns_[i];
        wd.dst[i] = dsts[i]; wd.scale[i] = scs[i];
    }
    for (int i = 0; i < 14; ++i) wd.tstart[i] = tst[i];

    const dim3 blk(256);

    convert_w_kernel<<<248, blk, 0, stream>>>(wd, WA);
    convert_bias_kernel<<<5, blk, 0, stream>>>(qb1, kb1, vb1, qb2, kb2, vb2, BA, QS1, QS2);

    add_pe_kernel<<<SEQ, blk, 0, stream>>>(x, F1, E1);

    // ================= encoder 1 (d=256, ff=1024, hd=32) =================
    gemm_bf16_kernel<0,0,1><<<dim3(6, 128), blk, 0, stream>>>(E1, WA + 0,      BA,   nullptr, Dq, 768, 256);
    flash_mfma_kernel<32><<<dim3(16, 64), blk, 0, stream>>>(Dq, E2);
    gemm_bf16_kernel<0,1,0><<<dim3(2, 128), blk, 0, stream>>>(E2, WA + 196608, ob1,  F2, nullptr, 256, 256);
    ln_residual_kernel<256,1><<<NTOK / 4, blk, 0, stream>>>(F2, F1, ln1g1, ln1b1, F1, E1);
    gemm_bf16_kernel<1,0,1><<<dim3(8, 128), blk, 0, stream>>>(E1, WA + 262144, f1b1, nullptr, Dq, 1024, 256);
    gemm_bf16_kernel<0,1,0><<<dim3(2, 128), blk, 0, stream>>>(Dq, WA + 524288, f2b1, F2, nullptr, 256, 1024);
    ln_residual_kernel<256,1><<<NTOK / 4, blk, 0, stream>>>(F2, F1, ln2g1, ln2b1, F1, E1);

    // ---- 256 -> 128 (fp32 residual base for enc2 + bf16 GEMM input) ----
    gemm_bf16_kernel<0,1,1><<<dim3(1, 128), blk, 0, stream>>>(E1, WA + 786432, dr1b, F2, E2, 128, 256);

    // ================= encoder 2 (d=128, ff=512, hd=16) =================
    gemm_bf16_kernel<0,0,1><<<dim3(3, 128), blk, 0, stream>>>(E2, WA + 819200, BA + 768, nullptr, Dq, 384, 128);
    flash_mfma_kernel<16><<<dim3(16, 64), blk, 0, stream>>>(Dq, E3);
    gemm_bf16_kernel<0,1,0><<<dim3(1, 128), blk, 0, stream>>>(E3, WA + 868352, ob2,  F1, nullptr, 128, 128);
    ln_residual_kernel<128,1><<<NTOK / 4, blk, 0, stream>>>(F1, F2, ln1g2, ln1b2, F2, E1);
    gemm_bf16_kernel<1,0,1><<<dim3(4, 128), blk, 0, stream>>>(E1, WA + 884736, f1b2, nullptr, Dq, 512, 128);
    gemm_bf16_kernel<0,1,0><<<dim3(1, 128), blk, 0, stream>>>(Dq, WA + 950272, f2b2, F1, nullptr, 128, 512);
    ln_residual_kernel<128,0><<<NTOK / 4, blk, 0, stream>>>(F1, F2, ln2g2, ln2b2, F2, E1);

    // ---- 128 -> 64, pool, head ----
    gemm_bias_kernel<0><<<dim3(1, NTOK / 64), blk, 0, stream>>>(F2, dr2w, dr2b, F1, NTOK, 64, 128);
    maxpool_kernel<<<BATCH, blk, 0, stream>>>(F1, F2);
    head_kernel<<<1, blk, 0, stream>>>(F2, dr3w, dr3b, dr4w, dr4b, (float*)d_out);
}